// Round 2
// baseline (1562.037 us; speedup 1.0000x reference)
//
#include <hip/hip_runtime.h>
#include <hip/hip_cooperative_groups.h>

namespace cg = cooperative_groups;

typedef unsigned short u16;
typedef u16 u16x8 __attribute__((ext_vector_type(8)));
typedef float f32x8 __attribute__((ext_vector_type(8)));

#define IN_DIM 1024
#define H_DIM  2048
#define V_DIM  50257
#define NEG_BIG (-1e30f)
#define COOP_GRID 1024

__device__ __forceinline__ float bf2f(u16 u) {
    union { unsigned int i; float f; } v;
    v.i = ((unsigned int)u) << 16;
    return v.f;
}

__device__ __forceinline__ u16 f2bf(float f) {
    union { float f; unsigned int i; } v;
    v.f = f;
    unsigned int i = v.i;
    i += 0x7fffu + ((i >> 16) & 1u);   // round-to-nearest-even
    return (u16)(i >> 16);
}

template<typename T>
__device__ __forceinline__ T ntl(const T* p) { return __builtin_nontemporal_load(p); }

__device__ __forceinline__ float wave_allreduce_sum(float v) {
    #pragma unroll
    for (int d = 32; d; d >>= 1) v += __shfl_xor(v, d, 64);
    return v;
}

__device__ __forceinline__ float sigmoidf(float x) { return 1.f / (1.f + __expf(-x)); }

__device__ __forceinline__ float ld_scalar(const void* p, int i, bool bf) {
    return bf ? bf2f(((const u16*)p)[i]) : ((const float*)p)[i];
}

// dtype probe from x's bit patterns (uniform verdict per wave; max byte offset 253 < 2048)
__device__ __forceinline__ bool probe_bf16(const void* x) {
    const u16* p = (const u16*)x;
    const int lane = threadIdx.x & 63;
    u16 w = p[2 * lane];
    int e = (w >> 7) & 0xFF;
    unsigned long long b = __ballot(e >= 0x60 && e <= 0x8F);
    return __popcll(b) > 40;
}

// ---- dot helpers: NVEC = (length / 512); batch-load then FMA ----
template<int NVEC>
__device__ __forceinline__ float dotN_bf(const u16x8* wp, const u16x8* vp, int lane) {
    u16x8 a[NVEC], v[NVEC];
    #pragma unroll
    for (int k = 0; k < NVEC; ++k) { a[k] = ntl(wp + lane + 64 * k); v[k] = vp[lane + 64 * k]; }
    float acc = 0.f;
    #pragma unroll
    for (int k = 0; k < NVEC; ++k)
        #pragma unroll
        for (int t = 0; t < 8; ++t) acc += bf2f(a[k][t]) * bf2f(v[k][t]);
    return acc;
}

template<int NVEC>
__device__ __forceinline__ float dotN_f32(const f32x8* wp, const f32x8* vp, int lane) {
    f32x8 a[NVEC], v[NVEC];
    #pragma unroll
    for (int k = 0; k < NVEC; ++k) { a[k] = ntl(wp + lane + 64 * k); v[k] = vp[lane + 64 * k]; }
    float acc = 0.f;
    #pragma unroll
    for (int k = 0; k < NVEC; ++k)
        #pragma unroll
        for (int t = 0; t < 8; ++t) acc += a[k][t] * v[k][t];
    return acc;
}

template<int NVEC>
__device__ __forceinline__ float dotN_bf_f32v(const u16x8* wp, const f32x8* vp, int lane) {
    u16x8 a[NVEC]; f32x8 v[NVEC];
    #pragma unroll
    for (int k = 0; k < NVEC; ++k) { a[k] = ntl(wp + lane + 64 * k); v[k] = vp[lane + 64 * k]; }
    float acc = 0.f;
    #pragma unroll
    for (int k = 0; k < NVEC; ++k)
        #pragma unroll
        for (int t = 0; t < 8; ++t) acc += bf2f(a[k][t]) * v[k][t];
    return acc;
}

// =======================================================================
// Fused cooperative kernel: lstm1 | gsync | lstm2 | gsync | logits |
// gsync | all-block logZ reduce | output write.
// grid = COOP_GRID x 256; __launch_bounds__(256,4) caps VGPR at 128 so
// 4 blocks/CU co-residency (1024 blocks on 256 CUs) is guaranteed.
// =======================================================================
__global__ __launch_bounds__(256, 4) void fused_kernel(
    const void* __restrict__ x, const void* __restrict__ h1, const void* __restrict__ c1,
    const void* __restrict__ h2, const void* __restrict__ c2,
    const void* __restrict__ W_ih1, const void* __restrict__ W_hh1,
    const void* __restrict__ b_ih1, const void* __restrict__ b_hh1,
    const void* __restrict__ W_ih2, const void* __restrict__ W_hh2,
    const void* __restrict__ b_ih2, const void* __restrict__ b_hh2,
    const void* __restrict__ W_out, const void* __restrict__ b_out,
    float* __restrict__ h1n, float* __restrict__ h2n,
    float* __restrict__ logits, float* __restrict__ pm, float* __restrict__ ps,
    void* __restrict__ out)
{
    cg::grid_group grid = cg::this_grid();
    const bool bf  = probe_bf16(x);
    const int wave = threadIdx.x >> 6;
    const int lane = threadIdx.x & 63;
    __shared__ float gs[4];
    __shared__ float sm[256], ss[256];

    // ---------------- phase A: LSTM layer 1 ----------------
    for (int j = blockIdx.x; j < H_DIM; j += gridDim.x) {
        const int row = wave * H_DIM + j;
        float acc;
        if (bf) {
            acc = dotN_bf<2>((const u16x8*)W_ih1 + (size_t)row * (IN_DIM / 8), (const u16x8*)x, lane)
                + dotN_bf<4>((const u16x8*)W_hh1 + (size_t)row * (H_DIM / 8), (const u16x8*)h1, lane);
        } else {
            acc = dotN_f32<2>((const f32x8*)W_ih1 + (size_t)row * (IN_DIM / 8), (const f32x8*)x, lane)
                + dotN_f32<4>((const f32x8*)W_hh1 + (size_t)row * (H_DIM / 8), (const f32x8*)h1, lane);
        }
        acc = wave_allreduce_sum(acc);
        if (lane == 0) gs[wave] = acc + ld_scalar(b_ih1, row, bf) + ld_scalar(b_hh1, row, bf);
        __syncthreads();
        if (threadIdx.x == 0) {
            float gi = sigmoidf(gs[0]);
            float gf = sigmoidf(gs[1]);
            float gg = tanhf(gs[2]);
            float go = sigmoidf(gs[3]);
            float c  = gf * ld_scalar(c1, j, bf) + gi * gg;
            h1n[j] = go * tanhf(c);
        }
        __syncthreads();
    }
    __threadfence();
    grid.sync();

    // ---------------- phase B: LSTM layer 2 (input h1n fp32) ----------------
    for (int j = blockIdx.x; j < H_DIM; j += gridDim.x) {
        const int row = wave * H_DIM + j;
        float acc;
        if (bf) {
            acc = dotN_bf_f32v<4>((const u16x8*)W_ih2 + (size_t)row * (H_DIM / 8), (const f32x8*)h1n, lane)
                + dotN_bf<4>((const u16x8*)W_hh2 + (size_t)row * (H_DIM / 8), (const u16x8*)h2, lane);
        } else {
            acc = dotN_f32<4>((const f32x8*)W_ih2 + (size_t)row * (H_DIM / 8), (const f32x8*)h1n, lane)
                + dotN_f32<4>((const f32x8*)W_hh2 + (size_t)row * (H_DIM / 8), (const f32x8*)h2, lane);
        }
        acc = wave_allreduce_sum(acc);
        if (lane == 0) gs[wave] = acc + ld_scalar(b_ih2, row, bf) + ld_scalar(b_hh2, row, bf);
        __syncthreads();
        if (threadIdx.x == 0) {
            float gi = sigmoidf(gs[0]);
            float gf = sigmoidf(gs[1]);
            float gg = tanhf(gs[2]);
            float go = sigmoidf(gs[3]);
            float c  = gf * ld_scalar(c2, j, bf) + gi * gg;
            h2n[j] = go * tanhf(c);
        }
        __syncthreads();
    }
    __threadfence();
    grid.sync();

    // ---------------- phase C: logits + per-wave online softmax partials ----------------
    float hreg[32];
    {
        const f32x8* hv = (const f32x8*)h2n;
        #pragma unroll
        for (int k = 0; k < 4; ++k) {
            f32x8 hh = hv[lane + 64 * k];
            #pragma unroll
            for (int t = 0; t < 8; ++t) hreg[8 * k + t] = hh[t];
        }
    }
    const int NW  = gridDim.x * 4;
    const int wid = blockIdx.x * 4 + wave;
    const int rpw = (V_DIM + NW - 1) / NW;
    const int rbeg = wid * rpw;
    const int rend = min(rbeg + rpw, V_DIM);
    float m = NEG_BIG, s = 0.f;
    for (int r = rbeg; r < rend; ++r) {
        float acc = 0.f;
        if (bf) {
            const u16x8* wr = (const u16x8*)W_out + (size_t)r * (H_DIM / 8) + lane;
            u16x8 a[4];
            #pragma unroll
            for (int k = 0; k < 4; ++k) a[k] = ntl(wr + 64 * k);
            #pragma unroll
            for (int k = 0; k < 4; ++k)
                #pragma unroll
                for (int t = 0; t < 8; ++t) acc += bf2f(a[k][t]) * hreg[8 * k + t];
        } else {
            const f32x8* wr = (const f32x8*)W_out + (size_t)r * (H_DIM / 8) + lane;
            f32x8 a[4];
            #pragma unroll
            for (int k = 0; k < 4; ++k) a[k] = ntl(wr + 64 * k);
            #pragma unroll
            for (int k = 0; k < 4; ++k)
                #pragma unroll
                for (int t = 0; t < 8; ++t) acc += a[k][t] * hreg[8 * k + t];
        }
        acc = wave_allreduce_sum(acc);
        const float lg = acc + ld_scalar(b_out, r, bf);
        if (lane == 0) logits[r] = lg;
        const float mn = fmaxf(m, lg);
        s = s * __expf(m - mn) + __expf(lg - mn);
        m = mn;
    }
    if (lane == 0) { pm[wid] = m; ps[wid] = s; }
    __threadfence();
    grid.sync();

    // ---------------- phase D: every block reduces all partials to logZ ----------------
    {
        float mm = NEG_BIG, sv = 0.f;
        for (int i = threadIdx.x; i < NW; i += 256) {
            float bm = pm[i], bs = ps[i];
            float mn = fmaxf(mm, bm);
            sv = sv * __expf(mm - mn) + bs * __expf(bm - mn);
            mm = mn;
        }
        sm[threadIdx.x] = mm; ss[threadIdx.x] = sv;
        __syncthreads();
        #pragma unroll
        for (int stride = 128; stride > 0; stride >>= 1) {
            if ((int)threadIdx.x < stride) {
                float m1 = sm[threadIdx.x], s1 = ss[threadIdx.x];
                float m2 = sm[threadIdx.x + stride], s2 = ss[threadIdx.x + stride];
                float mn = fmaxf(m1, m2);
                sm[threadIdx.x] = mn;
                ss[threadIdx.x] = s1 * __expf(m1 - mn) + s2 * __expf(m2 - mn);
            }
            __syncthreads();
        }
    }
    const float logZ = sm[0] + __logf(ss[0]);

    // ---------------- phase E: write output in probed dtype ----------------
    for (int i = blockIdx.x * 256 + threadIdx.x; i < V_DIM; i += gridDim.x * 256) {
        float v = logits[i] - logZ;
        if (bf) ((u16*)out)[i] = f2bf(v);
        else    ((float*)out)[i] = v;
    }
}

// =======================================================================
// Fallback path: 4 separate kernels (round-1 structure), used only if
// cooperative launch is unavailable.
// =======================================================================
__global__ __launch_bounds__(256) void lstm1_kernel(
    const void* __restrict__ x, const void* __restrict__ h1, const void* __restrict__ c1,
    const void* __restrict__ W_ih, const void* __restrict__ W_hh,
    const void* __restrict__ b_ih, const void* __restrict__ b_hh,
    float* __restrict__ h_out)
{
    const bool bf  = probe_bf16(x);
    const int j    = blockIdx.x;
    const int wave = threadIdx.x >> 6;
    const int lane = threadIdx.x & 63;
    const int row  = wave * H_DIM + j;

    float acc;
    if (bf) {
        acc = dotN_bf<2>((const u16x8*)W_ih + (size_t)row * (IN_DIM / 8), (const u16x8*)x, lane)
            + dotN_bf<4>((const u16x8*)W_hh + (size_t)row * (H_DIM / 8), (const u16x8*)h1, lane);
    } else {
        acc = dotN_f32<2>((const f32x8*)W_ih + (size_t)row * (IN_DIM / 8), (const f32x8*)x, lane)
            + dotN_f32<4>((const f32x8*)W_hh + (size_t)row * (H_DIM / 8), (const f32x8*)h1, lane);
    }
    acc = wave_allreduce_sum(acc);

    __shared__ float gs[4];
    if (lane == 0) gs[wave] = acc + ld_scalar(b_ih, row, bf) + ld_scalar(b_hh, row, bf);
    __syncthreads();
    if (threadIdx.x == 0) {
        float gi = sigmoidf(gs[0]);
        float gf = sigmoidf(gs[1]);
        float gg = tanhf(gs[2]);
        float go = sigmoidf(gs[3]);
        float c  = gf * ld_scalar(c1, j, bf) + gi * gg;
        h_out[j] = go * tanhf(c);
    }
}

__global__ __launch_bounds__(256) void lstm2_kernel(
    const void* __restrict__ x,
    const float* __restrict__ h1n, const void* __restrict__ h2, const void* __restrict__ c2,
    const void* __restrict__ W_ih, const void* __restrict__ W_hh,
    const void* __restrict__ b_ih, const void* __restrict__ b_hh,
    float* __restrict__ h_out)
{
    const bool bf  = probe_bf16(x);
    const int j    = blockIdx.x;
    const int wave = threadIdx.x >> 6;
    const int lane = threadIdx.x & 63;
    const int row  = wave * H_DIM + j;

    float acc;
    if (bf) {
        acc = dotN_bf_f32v<4>((const u16x8*)W_ih + (size_t)row * (H_DIM / 8), (const f32x8*)h1n, lane)
            + dotN_bf<4>((const u16x8*)W_hh + (size_t)row * (H_DIM / 8), (const u16x8*)h2, lane);
    } else {
        acc = dotN_f32<4>((const f32x8*)W_ih + (size_t)row * (H_DIM / 8), (const f32x8*)h1n, lane)
            + dotN_f32<4>((const f32x8*)W_hh + (size_t)row * (H_DIM / 8), (const f32x8*)h2, lane);
    }
    acc = wave_allreduce_sum(acc);

    __shared__ float gs[4];
    if (lane == 0) gs[wave] = acc + ld_scalar(b_ih, row, bf) + ld_scalar(b_hh, row, bf);
    __syncthreads();
    if (threadIdx.x == 0) {
        float gi = sigmoidf(gs[0]);
        float gf = sigmoidf(gs[1]);
        float gg = tanhf(gs[2]);
        float go = sigmoidf(gs[3]);
        float c  = gf * ld_scalar(c2, j, bf) + gi * gg;
        h_out[j] = go * tanhf(c);
    }
}

#define ROWS_PER_WAVE 8
#define ROWS_PER_BLOCK 32
__global__ __launch_bounds__(256) void logits_kernel(
    const void* __restrict__ x,
    const float* __restrict__ h2n, const void* __restrict__ W, const void* __restrict__ b,
    float* __restrict__ logits, float* __restrict__ pmax, float* __restrict__ psum)
{
    const bool bf  = probe_bf16(x);
    const int wave = threadIdx.x >> 6;
    const int lane = threadIdx.x & 63;

    float hreg[32];
    {
        const f32x8* hv = (const f32x8*)h2n;
        #pragma unroll
        for (int k = 0; k < 4; ++k) {
            f32x8 hh = hv[lane + 64 * k];
            #pragma unroll
            for (int t = 0; t < 8; ++t) hreg[8 * k + t] = hh[t];
        }
    }

    const int base = blockIdx.x * ROWS_PER_BLOCK + wave * ROWS_PER_WAVE;
    float m = NEG_BIG, s = 0.f;
    for (int rr = 0; rr < ROWS_PER_WAVE; ++rr) {
        const int r = base + rr;
        const int cr = min(r, V_DIM - 1);
        float acc = 0.f;
        if (bf) {
            const u16x8* wr = (const u16x8*)W + (size_t)cr * (H_DIM / 8) + lane;
            u16x8 a[4];
            #pragma unroll
            for (int k = 0; k < 4; ++k) a[k] = ntl(wr + 64 * k);
            #pragma unroll
            for (int k = 0; k < 4; ++k)
                #pragma unroll
                for (int t = 0; t < 8; ++t) acc += bf2f(a[k][t]) * hreg[8 * k + t];
        } else {
            const f32x8* wr = (const f32x8*)W + (size_t)cr * (H_DIM / 8) + lane;
            f32x8 a[4];
            #pragma unroll
            for (int k = 0; k < 4; ++k) a[k] = ntl(wr + 64 * k);
            #pragma unroll
            for (int k = 0; k < 4; ++k)
                #pragma unroll
                for (int t = 0; t < 8; ++t) acc += a[k][t] * hreg[8 * k + t];
        }
        acc = wave_allreduce_sum(acc);
        const float lg = acc + ld_scalar(b, cr, bf);
        const bool valid = (r < V_DIM);
        if (lane == 0 && valid) logits[r] = lg;
        if (valid) {
            const float mn = fmaxf(m, lg);
            s = s * __expf(m - mn) + __expf(lg - mn);
            m = mn;
        }
    }

    __shared__ float wm[4], wsv[4];
    if (lane == 0) { wm[wave] = m; wsv[wave] = s; }
    __syncthreads();
    if (threadIdx.x == 0) {
        float M = fmaxf(fmaxf(wm[0], wm[1]), fmaxf(wm[2], wm[3]));
        float S = 0.f;
        #pragma unroll
        for (int w = 0; w < 4; ++w) S += wsv[w] * __expf(wm[w] - M);
        pmax[blockIdx.x] = M;
        psum[blockIdx.x] = S;
    }
}

__global__ __launch_bounds__(256) void finalize_kernel(
    const void* __restrict__ x,
    const float* __restrict__ logits, const float* __restrict__ pmax,
    const float* __restrict__ psum, int nblk,
    void* __restrict__ out)
{
    const bool bf = probe_bf16(x);
    __shared__ float sm[256], ss[256];
    float m = NEG_BIG, s = 0.f;
    for (int i = threadIdx.x; i < nblk; i += 256) {
        float bm = pmax[i], bs = psum[i];
        float mn = fmaxf(m, bm);
        s = s * __expf(m - mn) + bs * __expf(bm - mn);
        m = mn;
    }
    sm[threadIdx.x] = m; ss[threadIdx.x] = s;
    __syncthreads();
    #pragma unroll
    for (int stride = 128; stride > 0; stride >>= 1) {
        if ((int)threadIdx.x < stride) {
            float m1 = sm[threadIdx.x], s1 = ss[threadIdx.x];
            float m2 = sm[threadIdx.x + stride], s2 = ss[threadIdx.x + stride];
            float mn = fmaxf(m1, m2);
            sm[threadIdx.x] = mn;
            ss[threadIdx.x] = s1 * __expf(m1 - mn) + s2 * __expf(m2 - mn);
        }
        __syncthreads();
    }
    const float logZ = sm[0] + __logf(ss[0]);
    const int i = blockIdx.x * 256 + threadIdx.x;
    if (i < V_DIM) {
        float v = logits[i] - logZ;
        if (bf) ((u16*)out)[i] = f2bf(v);
        else    ((float*)out)[i] = v;
    }
}

extern "C" void kernel_launch(void* const* d_in, const int* in_sizes, int n_in,
                              void* d_out, int out_size, void* d_ws, size_t ws_size,
                              hipStream_t stream)
{
    const void* x     = d_in[0];
    const void* h1    = d_in[1];
    const void* c1    = d_in[2];
    const void* h2    = d_in[3];
    const void* c2    = d_in[4];
    const void* W_ih1 = d_in[5];
    const void* W_hh1 = d_in[6];
    const void* b_ih1 = d_in[7];
    const void* b_hh1 = d_in[8];
    const void* W_ih2 = d_in[9];
    const void* W_hh2 = d_in[10];
    const void* b_ih2 = d_in[11];
    const void* b_hh2 = d_in[12];
    const void* W_out = d_in[13];
    const void* b_out = d_in[14];

    float* ws     = (float*)d_ws;
    float* h1n    = ws;                      // 2048 fp32
    float* h2n    = ws + 2048;               // 2048 fp32
    float* logits = ws + 4096;               // 50257 fp32 (padded to 50264)
    float* pm     = ws + 4096 + 50264;       // 4096 fp32 (fused: per-wave; fallback: per-block)
    float* psv    = pm + 4096;               // 4096 fp32

    // cooperative-launch support check (host-side query only; no stream ops)
    static int coop = -1;
    if (coop < 0) {
        int dev = 0, v = 0;
        hipGetDevice(&dev);
        if (hipDeviceGetAttribute(&v, hipDeviceAttributeCooperativeLaunch, dev) != hipSuccess) v = 0;
        coop = v;
    }

    bool launched = false;
    if (coop) {
        void* args[] = {
            (void*)&x, (void*)&h1, (void*)&c1, (void*)&h2, (void*)&c2,
            (void*)&W_ih1, (void*)&W_hh1, (void*)&b_ih1, (void*)&b_hh1,
            (void*)&W_ih2, (void*)&W_hh2, (void*)&b_ih2, (void*)&b_hh2,
            (void*)&W_out, (void*)&b_out,
            (void*)&h1n, (void*)&h2n, (void*)&logits, (void*)&pm, (void*)&psv,
            (void*)&d_out
        };
        hipError_t e = hipLaunchCooperativeKernel((const void*)fused_kernel,
                                                  dim3(COOP_GRID), dim3(256),
                                                  args, 0, stream);
        if (e == hipSuccess) {
            launched = true;
        } else {
            (void)hipGetLastError();   // clear sticky error before fallback
        }
    }

    if (!launched) {
        const int nblk3 = (V_DIM + ROWS_PER_BLOCK - 1) / ROWS_PER_BLOCK;  // 1571
        lstm1_kernel<<<H_DIM, 256, 0, stream>>>(x, h1, c1, W_ih1, W_hh1, b_ih1, b_hh1, h1n);
        lstm2_kernel<<<H_DIM, 256, 0, stream>>>(x, h1n, h2, c2, W_ih2, W_hh2, b_ih2, b_hh2, h2n);
        logits_kernel<<<nblk3, 256, 0, stream>>>(x, h2n, W_out, b_out, logits, pm, psv);
        finalize_kernel<<<(V_DIM + 255) / 256, 256, 0, stream>>>(x, logits, pm, psv, nblk3, d_out);
    }
}

// Round 3
// 685.496 us; speedup vs baseline: 2.2787x; 2.2787x over previous
//
#include <hip/hip_runtime.h>
#include <hip/hip_bf16.h>

typedef unsigned short u16;
typedef u16 u16x8 __attribute__((ext_vector_type(8)));
typedef float f32x8 __attribute__((ext_vector_type(8)));

#define IN_DIM 1024
#define H_DIM  2048
#define V_DIM  50257
#define NEG_BIG (-1e30f)

__device__ __forceinline__ float bf2f(u16 u) {
    union { unsigned int i; float f; } v;
    v.i = ((unsigned int)u) << 16;
    return v.f;
}

__device__ __forceinline__ u16 f2bf(float f) {
    union { float f; unsigned int i; } v;
    v.f = f;
    unsigned int i = v.i;
    i += 0x7fffu + ((i >> 16) & 1u);   // round-to-nearest-even
    return (u16)(i >> 16);
}

template<typename T>
__device__ __forceinline__ T ntl(const T* p) { return __builtin_nontemporal_load(p); }

// all-lane butterfly sum across the 64-lane wave
__device__ __forceinline__ float wave_allreduce_sum(float v) {
    #pragma unroll
    for (int d = 32; d; d >>= 1) v += __shfl_xor(v, d, 64);
    return v;
}

__device__ __forceinline__ float sigmoidf(float x) { return 1.f / (1.f + __expf(-x)); }

__device__ __forceinline__ float ld_scalar(const void* p, int i, bool bf) {
    return bf ? bf2f(((const u16*)p)[i]) : ((const float*)p)[i];
}

// ---------------- inline dtype probe: bf16 vs fp32, from x's bit patterns ----------------
// Even-indexed u16 words of a bf16 buffer hold bf16 values of ~N(0,1): exponent field in a
// narrow band (~100% hits). For an fp32 buffer they are low mantissa bits (uniform, ~19%).
// Uniform verdict per wave; max byte offset 253 < 2048, safe for either dtype of x.
__device__ __forceinline__ bool probe_bf16(const void* x) {
    const u16* p = (const u16*)x;
    const int lane = threadIdx.x & 63;
    u16 w = p[2 * lane];
    int e = (w >> 7) & 0xFF;
    unsigned long long b = __ballot(e >= 0x60 && e <= 0x8F);
    return __popcll(b) > 40;
}

// ---- dot helpers: NVEC = (length / 512); batch-load then FMA ----
template<int NVEC>
__device__ __forceinline__ float dotN_bf(const u16x8* wp, const u16x8* vp, int lane) {
    u16x8 a[NVEC], v[NVEC];
    #pragma unroll
    for (int k = 0; k < NVEC; ++k) { a[k] = ntl(wp + lane + 64 * k); v[k] = vp[lane + 64 * k]; }
    float acc = 0.f;
    #pragma unroll
    for (int k = 0; k < NVEC; ++k)
        #pragma unroll
        for (int t = 0; t < 8; ++t) acc += bf2f(a[k][t]) * bf2f(v[k][t]);
    return acc;
}

template<int NVEC>
__device__ __forceinline__ float dotN_f32(const f32x8* wp, const f32x8* vp, int lane) {
    f32x8 a[NVEC], v[NVEC];
    #pragma unroll
    for (int k = 0; k < NVEC; ++k) { a[k] = ntl(wp + lane + 64 * k); v[k] = vp[lane + 64 * k]; }
    float acc = 0.f;
    #pragma unroll
    for (int k = 0; k < NVEC; ++k)
        #pragma unroll
        for (int t = 0; t < 8; ++t) acc += a[k][t] * v[k][t];
    return acc;
}

template<int NVEC>
__device__ __forceinline__ float dotN_bf_f32v(const u16x8* wp, const f32x8* vp, int lane) {
    u16x8 a[NVEC]; f32x8 v[NVEC];
    #pragma unroll
    for (int k = 0; k < NVEC; ++k) { a[k] = ntl(wp + lane + 64 * k); v[k] = vp[lane + 64 * k]; }
    float acc = 0.f;
    #pragma unroll
    for (int k = 0; k < NVEC; ++k)
        #pragma unroll
        for (int t = 0; t < 8; ++t) acc += bf2f(a[k][t]) * v[k][t];
    return acc;
}

// ---------------- LSTM layer 1 ----------------
// grid = H_DIM blocks x 256 thr (4 waves); wave w computes gate-row w*H_DIM + j.
__global__ __launch_bounds__(256) void lstm1_kernel(
    const void* __restrict__ x, const void* __restrict__ h1, const void* __restrict__ c1,
    const void* __restrict__ W_ih, const void* __restrict__ W_hh,
    const void* __restrict__ b_ih, const void* __restrict__ b_hh,
    float* __restrict__ h_out)
{
    const bool bf  = probe_bf16(x);
    const int j    = blockIdx.x;
    const int wave = threadIdx.x >> 6;
    const int lane = threadIdx.x & 63;
    const int row  = wave * H_DIM + j;

    float acc;
    if (bf) {
        acc = dotN_bf<2>((const u16x8*)W_ih + (size_t)row * (IN_DIM / 8), (const u16x8*)x, lane)
            + dotN_bf<4>((const u16x8*)W_hh + (size_t)row * (H_DIM / 8), (const u16x8*)h1, lane);
    } else {
        acc = dotN_f32<2>((const f32x8*)W_ih + (size_t)row * (IN_DIM / 8), (const f32x8*)x, lane)
            + dotN_f32<4>((const f32x8*)W_hh + (size_t)row * (H_DIM / 8), (const f32x8*)h1, lane);
    }
    acc = wave_allreduce_sum(acc);

    __shared__ float gs[4];
    if (lane == 0) gs[wave] = acc + ld_scalar(b_ih, row, bf) + ld_scalar(b_hh, row, bf);
    __syncthreads();
    if (threadIdx.x == 0) {
        float gi = sigmoidf(gs[0]);
        float gf = sigmoidf(gs[1]);
        float gg = tanhf(gs[2]);
        float go = sigmoidf(gs[3]);
        float c  = gf * ld_scalar(c1, j, bf) + gi * gg;
        h_out[j] = go * tanhf(c);
    }
}

// ---------------- LSTM layer 2: input h1n is fp32 in ws ----------------
__global__ __launch_bounds__(256) void lstm2_kernel(
    const void* __restrict__ x,          // probe only
    const float* __restrict__ h1n, const void* __restrict__ h2, const void* __restrict__ c2,
    const void* __restrict__ W_ih, const void* __restrict__ W_hh,
    const void* __restrict__ b_ih, const void* __restrict__ b_hh,
    float* __restrict__ h_out)
{
    const bool bf  = probe_bf16(x);
    const int j    = blockIdx.x;
    const int wave = threadIdx.x >> 6;
    const int lane = threadIdx.x & 63;
    const int row  = wave * H_DIM + j;

    float acc;
    if (bf) {
        acc = dotN_bf_f32v<4>((const u16x8*)W_ih + (size_t)row * (H_DIM / 8), (const f32x8*)h1n, lane)
            + dotN_bf<4>((const u16x8*)W_hh + (size_t)row * (H_DIM / 8), (const u16x8*)h2, lane);
    } else {
        acc = dotN_f32<4>((const f32x8*)W_ih + (size_t)row * (H_DIM / 8), (const f32x8*)h1n, lane)
            + dotN_f32<4>((const f32x8*)W_hh + (size_t)row * (H_DIM / 8), (const f32x8*)h2, lane);
    }
    acc = wave_allreduce_sum(acc);

    __shared__ float gs[4];
    if (lane == 0) gs[wave] = acc + ld_scalar(b_ih, row, bf) + ld_scalar(b_hh, row, bf);
    __syncthreads();
    if (threadIdx.x == 0) {
        float gi = sigmoidf(gs[0]);
        float gf = sigmoidf(gs[1]);
        float gg = tanhf(gs[2]);
        float go = sigmoidf(gs[3]);
        float c  = gf * ld_scalar(c2, j, bf) + gi * gg;
        h_out[j] = go * tanhf(c);
    }
}

// ---------------- logits + per-block online softmax partials ----------------
// bf16 path: 4 row-pairs per wave, software-pipelined — pair p+1's 8 NT loads are
// issued BEFORE pair p's FMA/reduce/softmax epilogue, keeping 128 B/lane in flight.
#define ROWS_PER_WAVE 8
#define ROWS_PER_BLOCK 32
__global__ __launch_bounds__(256) void logits_kernel(
    const void* __restrict__ x,          // probe only
    const float* __restrict__ h2n, const void* __restrict__ W, const void* __restrict__ b,
    float* __restrict__ logits, float* __restrict__ pmax, float* __restrict__ psum)
{
    const bool bf  = probe_bf16(x);
    const int wave = threadIdx.x >> 6;
    const int lane = threadIdx.x & 63;

    // h2n in registers; element map: elem = 8*lane + 512*k + t (matches u16x8/f32x8 rows)
    float hreg[32];
    {
        const f32x8* hv = (const f32x8*)h2n;
        #pragma unroll
        for (int k = 0; k < 4; ++k) {
            f32x8 hh = hv[lane + 64 * k];
            #pragma unroll
            for (int t = 0; t < 8; ++t) hreg[8 * k + t] = hh[t];
        }
    }

    const int base = blockIdx.x * ROWS_PER_BLOCK + wave * ROWS_PER_WAVE;
    float m = NEG_BIG, s = 0.f;

    if (bf) {
        const u16x8* Wv = (const u16x8*)W;
        u16x8 ca0[4], ca1[4];   // current pair's weight regs
        u16x8 na0[4], na1[4];   // next pair's weight regs (prefetch)

        // prologue: load pair 0
        {
            const int c0 = min(base + 0, V_DIM - 1), c1 = min(base + 1, V_DIM - 1);
            const u16x8* w0 = Wv + (size_t)c0 * (H_DIM / 8) + lane;
            const u16x8* w1 = Wv + (size_t)c1 * (H_DIM / 8) + lane;
            #pragma unroll
            for (int k = 0; k < 4; ++k) { ca0[k] = ntl(w0 + 64 * k); ca1[k] = ntl(w1 + 64 * k); }
        }

        #pragma unroll
        for (int p = 0; p < 4; ++p) {
            // prefetch pair p+1 before touching pair p's data
            if (p < 3) {
                const int n0 = min(base + 2 * p + 2, V_DIM - 1);
                const int n1 = min(base + 2 * p + 3, V_DIM - 1);
                const u16x8* w0 = Wv + (size_t)n0 * (H_DIM / 8) + lane;
                const u16x8* w1 = Wv + (size_t)n1 * (H_DIM / 8) + lane;
                #pragma unroll
                for (int k = 0; k < 4; ++k) { na0[k] = ntl(w0 + 64 * k); na1[k] = ntl(w1 + 64 * k); }
            }

            // compute pair p: two independent FMA chains
            float acc0 = 0.f, acc1 = 0.f;
            #pragma unroll
            for (int k = 0; k < 4; ++k)
                #pragma unroll
                for (int t = 0; t < 8; ++t) {
                    const float hval = hreg[8 * k + t];
                    acc0 += bf2f(ca0[k][t]) * hval;
                    acc1 += bf2f(ca1[k][t]) * hval;
                }
            #pragma unroll
            for (int d = 32; d; d >>= 1) {
                acc0 += __shfl_xor(acc0, d, 64);
                acc1 += __shfl_xor(acc1, d, 64);
            }

            const int r0 = base + 2 * p, r1 = r0 + 1;
            const int c0 = min(r0, V_DIM - 1), c1 = min(r1, V_DIM - 1);
            const float l0 = acc0 + bf2f(((const u16*)b)[c0]);
            const float l1 = acc1 + bf2f(((const u16*)b)[c1]);
            const bool v0 = (r0 < V_DIM), v1 = (r1 < V_DIM);
            if (lane == 0) {
                if (v0) logits[r0] = l0;
                if (v1) logits[r1] = l1;
            }
            const float mx = fmaxf(v0 ? l0 : NEG_BIG, v1 ? l1 : NEG_BIG);
            if (mx > -1e29f) {                       // uniform across the wave
                const float mn = fmaxf(m, mx);
                s = s * __expf(m - mn)
                  + (v0 ? __expf(l0 - mn) : 0.f)
                  + (v1 ? __expf(l1 - mn) : 0.f);
                m = mn;
            }

            // rotate prefetch -> current (full unroll: pure register renaming)
            if (p < 3) {
                #pragma unroll
                for (int k = 0; k < 4; ++k) { ca0[k] = na0[k]; ca1[k] = na1[k]; }
            }
        }
    } else {
        #pragma unroll
        for (int rr = 0; rr < ROWS_PER_WAVE; ++rr) {
            const int r = base + rr;
            const int cr = min(r, V_DIM - 1);
            const f32x8* wr = (const f32x8*)W + (size_t)cr * (H_DIM / 8) + lane;
            f32x8 a[4];
            #pragma unroll
            for (int k = 0; k < 4; ++k) a[k] = ntl(wr + 64 * k);
            float acc = 0.f;
            #pragma unroll
            for (int k = 0; k < 4; ++k)
                #pragma unroll
                for (int t = 0; t < 8; ++t) acc += a[k][t] * hreg[8 * k + t];
            acc = wave_allreduce_sum(acc);
            const float lg = acc + ((const float*)b)[cr];
            const bool valid = (r < V_DIM);
            if (lane == 0 && valid) logits[r] = lg;
            if (valid) {
                const float mn = fmaxf(m, lg);
                s = s * __expf(m - mn) + __expf(lg - mn);
                m = mn;
            }
        }
    }

    __shared__ float wm[4], wsv[4];
    if (lane == 0) { wm[wave] = m; wsv[wave] = s; }
    __syncthreads();
    if (threadIdx.x == 0) {
        float M = fmaxf(fmaxf(wm[0], wm[1]), fmaxf(wm[2], wm[3]));
        float S = 0.f;
        #pragma unroll
        for (int w = 0; w < 4; ++w) S += wsv[w] * __expf(wm[w] - M);  // empty wave: 0*exp(very neg)=0
        pmax[blockIdx.x] = M;
        psum[blockIdx.x] = S;
    }
}

// ---------------- finalize: partials -> logZ; out = (logits - logZ) in probed dtype ----------------
__global__ __launch_bounds__(256) void finalize_kernel(
    const void* __restrict__ x,          // probe only
    const float* __restrict__ logits, const float* __restrict__ pmax,
    const float* __restrict__ psum, int nblk,
    void* __restrict__ out)
{
    const bool bf = probe_bf16(x);
    __shared__ float sm[256], ss[256];
    float m = NEG_BIG, s = 0.f;
    for (int i = threadIdx.x; i < nblk; i += 256) {
        float bm = pmax[i], bs = psum[i];
        float mn = fmaxf(m, bm);
        s = s * __expf(m - mn) + bs * __expf(bm - mn);
        m = mn;
    }
    sm[threadIdx.x] = m; ss[threadIdx.x] = s;
    __syncthreads();
    #pragma unroll
    for (int stride = 128; stride > 0; stride >>= 1) {
        if ((int)threadIdx.x < stride) {
            float m1 = sm[threadIdx.x], s1 = ss[threadIdx.x];
            float m2 = sm[threadIdx.x + stride], s2 = ss[threadIdx.x + stride];
            float mn = fmaxf(m1, m2);
            sm[threadIdx.x] = mn;
            ss[threadIdx.x] = s1 * __expf(m1 - mn) + s2 * __expf(m2 - mn);
        }
        __syncthreads();
    }
    const float logZ = sm[0] + __logf(ss[0]);
    const int i = blockIdx.x * 256 + threadIdx.x;
    if (i < V_DIM) {
        float v = logits[i] - logZ;
        if (bf) ((u16*)out)[i] = f2bf(v);
        else    ((float*)out)[i] = v;
    }
}

extern "C" void kernel_launch(void* const* d_in, const int* in_sizes, int n_in,
                              void* d_out, int out_size, void* d_ws, size_t ws_size,
                              hipStream_t stream)
{
    const void* x     = d_in[0];
    const void* h1    = d_in[1];
    const void* c1    = d_in[2];
    const void* h2    = d_in[3];
    const void* c2    = d_in[4];
    const void* W_ih1 = d_in[5];
    const void* W_hh1 = d_in[6];
    const void* b_ih1 = d_in[7];
    const void* b_hh1 = d_in[8];
    const void* W_ih2 = d_in[9];
    const void* W_hh2 = d_in[10];
    const void* b_ih2 = d_in[11];
    const void* b_hh2 = d_in[12];
    const void* W_out = d_in[13];
    const void* b_out = d_in[14];

    float* ws     = (float*)d_ws;
    float* h1n    = ws;                    // 2048 fp32
    float* h2n    = ws + 2048;             // 2048 fp32
    float* logits = ws + 4096;             // 50257 fp32 (padded to 50264)
    float* pmax   = ws + 4096 + 50264;     // 1571 fp32 (padded to 1576)
    float* psum   = pmax + 1576;           // 1571 fp32 (padded to 1576)

    const int nblk3 = (V_DIM + ROWS_PER_BLOCK - 1) / ROWS_PER_BLOCK;  // 1571

    lstm1_kernel<<<H_DIM, 256, 0, stream>>>(x, h1, c1, W_ih1, W_hh1, b_ih1, b_hh1, h1n);
    lstm2_kernel<<<H_DIM, 256, 0, stream>>>(x, h1n, h2, c2, W_ih2, W_hh2, b_ih2, b_hh2, h2n);
    logits_kernel<<<nblk3, 256, 0, stream>>>(x, h2n, W_out, b_out, logits, pmax, psum);
    finalize_kernel<<<(V_DIM + 255) / 256, 256, 0, stream>>>(x, logits, pmax, psum, nblk3, d_out);
}